// Round 1
// baseline (547.025 us; speedup 1.0000x reference)
//
#include <hip/hip_runtime.h>
#include <stdint.h>

typedef __attribute__((ext_vector_type(8))) short bf16x8;   // 8 bf16 in 4 VGPRs (guide §3)
typedef __attribute__((ext_vector_type(4))) float f32x4;
typedef __attribute__((ext_vector_type(4))) unsigned short u16x4;
typedef unsigned short u16;

__device__ __forceinline__ u16 f2b(float f) {               // RTN f32->bf16
  uint32_t u = __builtin_bit_cast(uint32_t, f);
  u += 0x7FFFu + ((u >> 16) & 1u);
  return (u16)(u >> 16);
}
__device__ __forceinline__ float b2f(u16 v) {
  uint32_t u = ((uint32_t)v) << 16;
  return __builtin_bit_cast(float, u);
}
__device__ __forceinline__ f32x4 mfma16(bf16x8 a, bf16x8 b, f32x4 c) {
  return __builtin_amdgcn_mfma_f32_16x16x32_bf16(a, b, c, 0, 0, 0);
}
__device__ __forceinline__ void gload_lds16(const void* g, void* l) {
  __builtin_amdgcn_global_load_lds((const __attribute__((address_space(1))) unsigned int*)g,
                                   (__attribute__((address_space(3))) unsigned int*)l, 16, 0, 0);
}

// ---------------- conversion / small kernels ----------------
__global__ __launch_bounds__(256) void cvt_k(const float* __restrict__ src, u16* __restrict__ dst, int n) {
  int i = (blockIdx.x * 256 + threadIdx.x) * 4;
  if (i >= n) return;
  float4 v = *(const float4*)(src + i);
  u16x4 o; o[0] = f2b(v.x); o[1] = f2b(v.y); o[2] = f2b(v.z); o[3] = f2b(v.w);
  *(u16x4*)(dst + i) = o;
}

__global__ __launch_bounds__(256) void bcat_k(const float* __restrict__ bq, const float* __restrict__ bk,
                                              const float* __restrict__ bv, float* __restrict__ bcat) {
  int i = blockIdx.x * 256 + threadIdx.x;   // 5120 total
  bcat[i] = (i < 2048) ? bq[i] : ((i < 4096) ? bk[i - 2048] : bv[i - 4096]);
}

__global__ void lam_k(const float* __restrict__ lq1, const float* __restrict__ lk1,
                      const float* __restrict__ lq2, const float* __restrict__ lk2,
                      float* __restrict__ lam) {
  int h = threadIdx.x;
  if (h < 16) {
    float d1 = 0.f, d2 = 0.f;
    for (int i = 0; i < 64; i++) {
      d1 += lq1[h * 64 + i] * lk1[h * 64 + i];
      d2 += lq2[h * 64 + i] * lk2[h * 64 + i];
    }
    lam[h] = 0.2f + __expf(d1) - __expf(d2);  // LAMBDA_INIT = 0.2
  }
}

// In-place RoPE on q and k, layout (B*H*S) x 128, both 64-dim halves rotated.
__global__ __launch_bounds__(256) void rope_k(u16* __restrict__ q, u16* __restrict__ k) {
  int u = blockIdx.x * 256 + threadIdx.x;   // 65536 rows * 32 pairs
  int i = u & 31;
  int row = u >> 5;
  int s = row & 2047;
  float inv = __expf(-9.210340371976184f * (float)i * (1.f / 32.f)); // 10000^(-i/32)
  float ang = (float)s * inv;
  float c = cosf(ang), sn = sinf(ang);      // accurate range reduction for large args
  size_t base = (size_t)row * 128;
#pragma unroll
  for (int hf = 0; hf < 2; hf++) {
    size_t p = base + hf * 64 + i;
    float a = b2f(q[p]), b = b2f(q[p + 32]);
    q[p] = f2b(a * c - b * sn);
    q[p + 32] = f2b(a * sn + b * c);
    float ka = b2f(k[p]), kb = b2f(k[p + 32]);
    k[p] = f2b(ka * c - kb * sn);
    k[p + 32] = f2b(ka * sn + kb * c);
  }
}

// ---------------- GEMM (m97-style 128x128 tile, BK=32, 4 waves) ----------------
#define KD 1024

__global__ __launch_bounds__(256) void gemm_qkv(
    const u16* __restrict__ A, const u16* __restrict__ B, const float* __restrict__ bcat,
    u16* __restrict__ qout, u16* __restrict__ kout, u16* __restrict__ vout) {
  __shared__ __align__(16) u16 Al[128 * 32];
  __shared__ __align__(16) u16 Bl[128 * 32];
  const int t = threadIdx.x;
  const int w = t >> 6;
  const int l = t & 63;
  const int lr = l & 15, lg = l >> 4, lk8 = lg * 8;
  const int wm = (w >> 1) * 64, wn = (w & 1) * 64;
  const int n0 = blockIdx.x * 128, m0 = blockIdx.y * 128;
  f32x4 acc[4][4] = {};
  for (int k0 = 0; k0 < KD; k0 += 32) {
    __syncthreads();
#pragma unroll
    for (int i = 0; i < 2; i++) {
      int c = i * 256 + t;
      gload_lds16(A + (size_t)(m0 + (c >> 2)) * KD + k0 + (c & 3) * 8, (char*)Al + i * 4096 + w * 1024);
      gload_lds16(B + (size_t)(n0 + (c >> 2)) * KD + k0 + (c & 3) * 8, (char*)Bl + i * 4096 + w * 1024);
    }
    __syncthreads();
    bf16x8 af[4], bfr[4];
#pragma unroll
    for (int mi = 0; mi < 4; mi++) af[mi] = *(const bf16x8*)(Al + (wm + mi * 16 + lr) * 32 + lk8);
#pragma unroll
    for (int ni = 0; ni < 4; ni++) bfr[ni] = *(const bf16x8*)(Bl + (wn + ni * 16 + lr) * 32 + lk8);
#pragma unroll
    for (int mi = 0; mi < 4; mi++)
#pragma unroll
      for (int ni = 0; ni < 4; ni++)
        acc[mi][ni] = mfma16(af[mi], bfr[ni], acc[mi][ni]);
  }
  // epilogue: +bias, bf16, scatter into (B,H,S,·)
#pragma unroll
  for (int mi = 0; mi < 4; mi++) {
#pragma unroll
    for (int ni = 0; ni < 4; ni++) {
#pragma unroll
      for (int r = 0; r < 4; r++) {
        int m = m0 + wm + mi * 16 + lg * 4 + r;
        int n = n0 + wn + ni * 16 + lr;
        float v = acc[mi][ni][r] + bcat[n];
        int b = m >> 11, s = m & 2047;
        u16 bv = f2b(v);
        if (n < 2048) {
          int h = n >> 7, d = n & 127;
          qout[((size_t)(b * 16 + h) * 2048 + s) * 128 + d] = bv;
        } else if (n < 4096) {
          int nk = n - 2048, h = nk >> 7, d = nk & 127;
          kout[((size_t)(b * 16 + h) * 2048 + s) * 128 + d] = bv;
        } else {
          int nv = n - 4096, h = nv >> 6, d = nv & 63;
          vout[((size_t)(b * 16 + h) * 2048 + s) * 64 + d] = bv;
        }
      }
    }
  }
}

__global__ __launch_bounds__(256) void gemm_wo(
    const u16* __restrict__ A, const u16* __restrict__ B, const float* __restrict__ bo,
    float* __restrict__ out) {
  __shared__ __align__(16) u16 Al[128 * 32];
  __shared__ __align__(16) u16 Bl[128 * 32];
  const int t = threadIdx.x;
  const int w = t >> 6;
  const int l = t & 63;
  const int lr = l & 15, lg = l >> 4, lk8 = lg * 8;
  const int wm = (w >> 1) * 64, wn = (w & 1) * 64;
  const int n0 = blockIdx.x * 128, m0 = blockIdx.y * 128;
  f32x4 acc[4][4] = {};
  for (int k0 = 0; k0 < KD; k0 += 32) {
    __syncthreads();
#pragma unroll
    for (int i = 0; i < 2; i++) {
      int c = i * 256 + t;
      gload_lds16(A + (size_t)(m0 + (c >> 2)) * KD + k0 + (c & 3) * 8, (char*)Al + i * 4096 + w * 1024);
      gload_lds16(B + (size_t)(n0 + (c >> 2)) * KD + k0 + (c & 3) * 8, (char*)Bl + i * 4096 + w * 1024);
    }
    __syncthreads();
    bf16x8 af[4], bfr[4];
#pragma unroll
    for (int mi = 0; mi < 4; mi++) af[mi] = *(const bf16x8*)(Al + (wm + mi * 16 + lr) * 32 + lk8);
#pragma unroll
    for (int ni = 0; ni < 4; ni++) bfr[ni] = *(const bf16x8*)(Bl + (wn + ni * 16 + lr) * 32 + lk8);
#pragma unroll
    for (int mi = 0; mi < 4; mi++)
#pragma unroll
      for (int ni = 0; ni < 4; ni++)
        acc[mi][ni] = mfma16(af[mi], bfr[ni], acc[mi][ni]);
  }
#pragma unroll
  for (int mi = 0; mi < 4; mi++) {
#pragma unroll
    for (int ni = 0; ni < 4; ni++) {
#pragma unroll
      for (int r = 0; r < 4; r++) {
        int m = m0 + wm + mi * 16 + lg * 4 + r;
        int n = n0 + wn + ni * 16 + lr;
        out[(size_t)m * 1024 + n] = acc[mi][ni][r] + bo[n];
      }
    }
  }
}

// ---------------- differential flash attention ----------------
__device__ __forceinline__ void online_update(
    f32x4 s[4], int q0w, int k0, int lr, int lg,
    float m[4], float lsum[4], f32x4 O[4], u16* Pw) {
#pragma unroll
  for (int r = 0; r < 4; r++) {
    int qg = q0w + lg * 4 + r;
    float pv[4];
    float mx = -1e30f;
#pragma unroll
    for (int ct = 0; ct < 4; ct++) {
      int kg = k0 + ct * 16 + lr;
      float sv = (kg <= qg) ? s[ct][r] * 0.125f : -1e30f;
      pv[ct] = sv;
      mx = fmaxf(mx, sv);
    }
#pragma unroll
    for (int d = 1; d < 16; d <<= 1) mx = fmaxf(mx, __shfl_xor(mx, d));
    float mn = fmaxf(m[r], mx);
    float f = __expf(m[r] - mn);
    float rs = 0.f;
#pragma unroll
    for (int ct = 0; ct < 4; ct++) {
      float p = __expf(pv[ct] - mn);
      pv[ct] = p;
      rs += p;
    }
#pragma unroll
    for (int d = 1; d < 16; d <<= 1) rs += __shfl_xor(rs, d);
    lsum[r] = lsum[r] * f + rs;
    m[r] = mn;
#pragma unroll
    for (int dt = 0; dt < 4; dt++) O[dt][r] *= f;
#pragma unroll
    for (int ct = 0; ct < 4; ct++) Pw[(lg * 4 + r) * 72 + ct * 16 + lr] = f2b(pv[ct]);
  }
}

__device__ __forceinline__ void pv_acc(const u16* Pw, const u16* Vt, int lr, int lk8, f32x4 O[4]) {
#pragma unroll
  for (int sl = 0; sl < 2; sl++) {
    bf16x8 pf = *(const bf16x8*)(Pw + lr * 72 + sl * 32 + lk8);
#pragma unroll
    for (int dt = 0; dt < 4; dt++) {
      bf16x8 vf = *(const bf16x8*)(Vt + (dt * 16 + lr) * 72 + sl * 32 + lk8);
      O[dt] = mfma16(pf, vf, O[dt]);
    }
  }
}

__global__ __launch_bounds__(256) void diff_attn(
    const u16* __restrict__ Q, const u16* __restrict__ Kk, const u16* __restrict__ V,
    const float* __restrict__ lamv, const float* __restrict__ hnw, u16* __restrict__ Aout) {
  __shared__ __align__(16) u16 Kl[64 * 128];
  __shared__ __align__(16) u16 Vt[64 * 72];
  __shared__ __align__(16) u16 Pl[4][16 * 72];
  const int t = threadIdx.x, w = t >> 6, l = t & 63;
  const int lr = l & 15, lg = l >> 4, lk8 = lg * 8;
  const int bid = blockIdx.x;
  const int qt = 31 - (bid & 31);           // heavy blocks first
  const int h = (bid >> 5) & 15, b = bid >> 9;
  const int q0 = qt * 64;
  const size_t bh = (size_t)b * 16 + h;
  const u16* Qb = Q + bh * 2048 * 128;
  const u16* Kb = Kk + bh * 2048 * 128;
  const u16* Vb = V + bh * 2048 * 64;
  const float lam = lamv[h];
  bf16x8 qf[2][2];
#pragma unroll
  for (int hf = 0; hf < 2; hf++)
#pragma unroll
    for (int sl = 0; sl < 2; sl++)
      qf[hf][sl] = *(const bf16x8*)(Qb + (size_t)(q0 + w * 16 + lr) * 128 + hf * 64 + sl * 32 + lk8);
  f32x4 O1[4] = {}, O2[4] = {};
  float m1[4], l1[4], m2[4], l2[4];
#pragma unroll
  for (int r = 0; r < 4; r++) { m1[r] = -1e30f; l1[r] = 0.f; m2[r] = -1e30f; l2[r] = 0.f; }
  const int nkt = qt + 1;
  for (int kt = 0; kt < nkt; kt++) {
    const int k0 = kt * 64;
    __syncthreads();
    const u16* Ks = Kb + (size_t)k0 * 128;
#pragma unroll
    for (int i = 0; i < 4; i++)
      gload_lds16(Ks + (i * 256 + t) * 8, (char*)Kl + i * 4096 + w * 1024);
    {
      int vr = t >> 2, vc = (t & 3) * 16;
      const u16* vp = Vb + (size_t)(k0 + vr) * 64 + vc;
      bf16x8 v0 = *(const bf16x8*)vp;
      bf16x8 v1 = *(const bf16x8*)(vp + 8);
#pragma unroll
      for (int j = 0; j < 8; j++) Vt[(vc + j) * 72 + vr] = (u16)v0[j];
#pragma unroll
      for (int j = 0; j < 8; j++) Vt[(vc + 8 + j) * 72 + vr] = (u16)v1[j];
    }
    __syncthreads();
    f32x4 s1[4] = {}, s2[4] = {};
#pragma unroll
    for (int ct = 0; ct < 4; ct++) {
#pragma unroll
      for (int sl = 0; sl < 2; sl++) {
        bf16x8 kf1 = *(const bf16x8*)(Kl + (ct * 16 + lr) * 128 + sl * 32 + lk8);
        bf16x8 kf2 = *(const bf16x8*)(Kl + (ct * 16 + lr) * 128 + 64 + sl * 32 + lk8);
        s1[ct] = mfma16(qf[0][sl], kf1, s1[ct]);
        s2[ct] = mfma16(qf[1][sl], kf2, s2[ct]);
      }
    }
    online_update(s1, q0 + w * 16, k0, lr, lg, m1, l1, O1, Pl[w]);
    pv_acc(Pl[w], Vt, lr, lk8, O1);
    online_update(s2, q0 + w * 16, k0, lr, lg, m2, l2, O2, Pl[w]);
    pv_acc(Pl[w], Vt, lr, lk8, O2);
  }
  // epilogue: diff-combine, RMSNorm over hd=64, head weight, (1-lambda_init)=0.8
  float rr[4];
  f32x4 ov[4];
#pragma unroll
  for (int r = 0; r < 4; r++) {
    float i1 = 1.f / l1[r], i2 = lam / l2[r];
    float ss = 0.f;
#pragma unroll
    for (int dt = 0; dt < 4; dt++) {
      float o = O1[dt][r] * i1 - O2[dt][r] * i2;
      ov[dt][r] = o;
      ss += o * o;
    }
#pragma unroll
    for (int d = 1; d < 16; d <<= 1) ss += __shfl_xor(ss, d);
    rr[r] = rsqrtf(ss * (1.f / 64.f) + 1e-6f) * 0.8f;
  }
#pragma unroll
  for (int dt = 0; dt < 4; dt++) {
    float hw = hnw[h * 64 + dt * 16 + lr];
#pragma unroll
    for (int r = 0; r < 4; r++) {
      int qg = q0 + w * 16 + lg * 4 + r;
      Aout[((size_t)b * 2048 + qg) * 1024 + h * 64 + dt * 16 + lr] = f2b(ov[dt][r] * rr[r] * hw);
    }
  }
}

// ---------------- launch ----------------
extern "C" void kernel_launch(void* const* d_in, const int* in_sizes, int n_in,
                              void* d_out, int out_size, void* d_ws, size_t ws_size,
                              hipStream_t stream) {
  const float* x   = (const float*)d_in[0];
  const float* Wq  = (const float*)d_in[1];
  const float* bq  = (const float*)d_in[2];
  const float* Wk  = (const float*)d_in[3];
  const float* bk  = (const float*)d_in[4];
  const float* Wv  = (const float*)d_in[5];
  const float* bv  = (const float*)d_in[6];
  const float* Wo  = (const float*)d_in[7];
  const float* bo  = (const float*)d_in[8];
  const float* hnw = (const float*)d_in[9];
  const float* lq1 = (const float*)d_in[10];
  const float* lk1 = (const float*)d_in[11];
  const float* lq2 = (const float*)d_in[12];
  const float* lk2 = (const float*)d_in[13];
  float* out = (float*)d_out;
  char* ws = (char*)d_ws;

  u16*   x_bf  = (u16*)(ws);                 //  8,388,608 B  (4096x1024 bf16)
  u16*   wcat  = (u16*)(ws + 8388608);       // 10,485,760 B  (5120x1024 bf16: Wq|Wk|Wv)
  u16*   wo_bf = (u16*)(ws + 18874368);      //  2,097,152 B
  float* bcat  = (float*)(ws + 20971520);    //     20,480 B
  float* lam   = (float*)(ws + 20992000);    //         64 B
  u16*   q_r   = (u16*)(ws + 20992064);      // 16,777,216 B  (B,H,S,128)
  u16*   k_r   = (u16*)(ws + 37769280);      // 16,777,216 B
  u16*   v_s   = (u16*)(ws + 54546496);      //  8,388,608 B  (B,H,S,64)
  u16*   a_out = (u16*)(ws + 62935104);      //  8,388,608 B  (4096x1024 bf16)

  cvt_k<<<4096, 256, 0, stream>>>(x, x_bf, 4194304);
  cvt_k<<<2048, 256, 0, stream>>>(Wq, wcat, 2097152);
  cvt_k<<<2048, 256, 0, stream>>>(Wk, wcat + 2097152, 2097152);
  cvt_k<<<1024, 256, 0, stream>>>(Wv, wcat + 4194304, 1048576);
  cvt_k<<<1024, 256, 0, stream>>>(Wo, wo_bf, 1048576);
  bcat_k<<<20, 256, 0, stream>>>(bq, bk, bv, bcat);
  lam_k<<<1, 64, 0, stream>>>(lq1, lk1, lq2, lk2, lam);
  gemm_qkv<<<dim3(40, 32), 256, 0, stream>>>(x_bf, wcat, bcat, q_r, k_r, v_s);
  rope_k<<<8192, 256, 0, stream>>>(q_r, k_r);
  diff_attn<<<1024, 256, 0, stream>>>(q_r, k_r, v_s, lam, hnw, a_out);
  gemm_wo<<<dim3(8, 32), 256, 0, stream>>>(a_out, wo_bf, bo, out);
}

// Round 2
// 502.846 us; speedup vs baseline: 1.0879x; 1.0879x over previous
//
#include <hip/hip_runtime.h>
#include <stdint.h>

typedef __attribute__((ext_vector_type(8))) short bf16x8;   // 8 bf16 in 4 VGPRs (guide §3)
typedef __attribute__((ext_vector_type(4))) float f32x4;
typedef __attribute__((ext_vector_type(4))) unsigned short u16x4;
typedef unsigned short u16;

__device__ __forceinline__ u16 f2b(float f) {               // RTN f32->bf16
  uint32_t u = __builtin_bit_cast(uint32_t, f);
  u += 0x7FFFu + ((u >> 16) & 1u);
  return (u16)(u >> 16);
}
__device__ __forceinline__ float b2f(u16 v) {
  uint32_t u = ((uint32_t)v) << 16;
  return __builtin_bit_cast(float, u);
}
__device__ __forceinline__ f32x4 mfma16(bf16x8 a, bf16x8 b, f32x4 c) {
  return __builtin_amdgcn_mfma_f32_16x16x32_bf16(a, b, c, 0, 0, 0);
}
__device__ __forceinline__ void gload_lds16(const void* g, void* l) {
  __builtin_amdgcn_global_load_lds((const __attribute__((address_space(1))) unsigned int*)g,
                                   (__attribute__((address_space(3))) unsigned int*)l, 16, 0, 0);
}

// ---------------- conversion / small kernels ----------------
__global__ __launch_bounds__(256) void cvt_k(const float* __restrict__ src, u16* __restrict__ dst, int n) {
  int i = (blockIdx.x * 256 + threadIdx.x) * 4;
  if (i >= n) return;
  float4 v = *(const float4*)(src + i);
  u16x4 o; o[0] = f2b(v.x); o[1] = f2b(v.y); o[2] = f2b(v.z); o[3] = f2b(v.w);
  *(u16x4*)(dst + i) = o;
}

__global__ __launch_bounds__(256) void bcat_k(const float* __restrict__ bq, const float* __restrict__ bk,
                                              const float* __restrict__ bv, float* __restrict__ bcat) {
  int i = blockIdx.x * 256 + threadIdx.x;   // 5120 total
  bcat[i] = (i < 2048) ? bq[i] : ((i < 4096) ? bk[i - 2048] : bv[i - 4096]);
}

__global__ void lam_k(const float* __restrict__ lq1, const float* __restrict__ lk1,
                      const float* __restrict__ lq2, const float* __restrict__ lk2,
                      float* __restrict__ lam) {
  int h = threadIdx.x;
  if (h < 16) {
    float d1 = 0.f, d2 = 0.f;
    for (int i = 0; i < 64; i++) {
      d1 += lq1[h * 64 + i] * lk1[h * 64 + i];
      d2 += lq2[h * 64 + i] * lk2[h * 64 + i];
    }
    lam[h] = 0.2f + __expf(d1) - __expf(d2);  // LAMBDA_INIT = 0.2
  }
}

// In-place RoPE on q and k, layout (B*H*S) x 128, both 64-dim halves rotated.
__global__ __launch_bounds__(256) void rope_k(u16* __restrict__ q, u16* __restrict__ k) {
  int u = blockIdx.x * 256 + threadIdx.x;   // 65536 rows * 32 pairs
  int i = u & 31;
  int row = u >> 5;
  int s = row & 2047;
  float inv = __expf(-9.210340371976184f * (float)i * (1.f / 32.f)); // 10000^(-i/32)
  float ang = (float)s * inv;
  float c = cosf(ang), sn = sinf(ang);      // accurate range reduction for large args
  size_t base = (size_t)row * 128;
#pragma unroll
  for (int hf = 0; hf < 2; hf++) {
    size_t p = base + hf * 64 + i;
    float a = b2f(q[p]), b = b2f(q[p + 32]);
    q[p] = f2b(a * c - b * sn);
    q[p + 32] = f2b(a * sn + b * c);
    float ka = b2f(k[p]), kb = b2f(k[p + 32]);
    k[p] = f2b(ka * c - kb * sn);
    k[p + 32] = f2b(ka * sn + kb * c);
  }
}

// ---------------- GEMM (m97-style 128x128 tile, BK=32, 4 waves) ----------------
#define KD 1024

__global__ __launch_bounds__(256) void gemm_qkv(
    const u16* __restrict__ A, const u16* __restrict__ B, const float* __restrict__ bcat,
    u16* __restrict__ qout, u16* __restrict__ kout, u16* __restrict__ vout) {
  __shared__ __align__(16) u16 Al[128 * 32];
  __shared__ __align__(16) u16 Bl[128 * 32];
  const int t = threadIdx.x;
  const int w = t >> 6;
  const int l = t & 63;
  const int lr = l & 15, lg = l >> 4, lk8 = lg * 8;
  const int wm = (w >> 1) * 64, wn = (w & 1) * 64;
  const int n0 = blockIdx.x * 128, m0 = blockIdx.y * 128;
  f32x4 acc[4][4] = {};
  for (int k0 = 0; k0 < KD; k0 += 32) {
    __syncthreads();
#pragma unroll
    for (int i = 0; i < 2; i++) {
      int c = i * 256 + t;
      gload_lds16(A + (size_t)(m0 + (c >> 2)) * KD + k0 + (c & 3) * 8, (char*)Al + i * 4096 + w * 1024);
      gload_lds16(B + (size_t)(n0 + (c >> 2)) * KD + k0 + (c & 3) * 8, (char*)Bl + i * 4096 + w * 1024);
    }
    __syncthreads();
    bf16x8 af[4], bfr[4];
#pragma unroll
    for (int mi = 0; mi < 4; mi++) af[mi] = *(const bf16x8*)(Al + (wm + mi * 16 + lr) * 32 + lk8);
#pragma unroll
    for (int ni = 0; ni < 4; ni++) bfr[ni] = *(const bf16x8*)(Bl + (wn + ni * 16 + lr) * 32 + lk8);
#pragma unroll
    for (int mi = 0; mi < 4; mi++)
#pragma unroll
      for (int ni = 0; ni < 4; ni++)
        acc[mi][ni] = mfma16(af[mi], bfr[ni], acc[mi][ni]);
  }
  // epilogue: +bias, bf16, scatter into (B,H,S,·); V goes out TRANSPOSED: [b][h][d][S]
#pragma unroll
  for (int mi = 0; mi < 4; mi++) {
#pragma unroll
    for (int ni = 0; ni < 4; ni++) {
#pragma unroll
      for (int r = 0; r < 4; r++) {
        int m = m0 + wm + mi * 16 + lg * 4 + r;
        int n = n0 + wn + ni * 16 + lr;
        float v = acc[mi][ni][r] + bcat[n];
        int b = m >> 11, s = m & 2047;
        u16 bv = f2b(v);
        if (n < 2048) {
          int h = n >> 7, d = n & 127;
          qout[((size_t)(b * 16 + h) * 2048 + s) * 128 + d] = bv;
        } else if (n < 4096) {
          int nk = n - 2048, h = nk >> 7, d = nk & 127;
          kout[((size_t)(b * 16 + h) * 2048 + s) * 128 + d] = bv;
        } else {
          int nv = n - 4096, h = nv >> 6, d = nv & 63;
          vout[((size_t)(b * 16 + h) * 64 + d) * 2048 + s] = bv;   // V^T layout
        }
      }
    }
  }
}

__global__ __launch_bounds__(256) void gemm_wo(
    const u16* __restrict__ A, const u16* __restrict__ B, const float* __restrict__ bo,
    float* __restrict__ out) {
  __shared__ __align__(16) u16 Al[128 * 32];
  __shared__ __align__(16) u16 Bl[128 * 32];
  const int t = threadIdx.x;
  const int w = t >> 6;
  const int l = t & 63;
  const int lr = l & 15, lg = l >> 4, lk8 = lg * 8;
  const int wm = (w >> 1) * 64, wn = (w & 1) * 64;
  const int n0 = blockIdx.x * 128, m0 = blockIdx.y * 128;
  f32x4 acc[4][4] = {};
  for (int k0 = 0; k0 < KD; k0 += 32) {
    __syncthreads();
#pragma unroll
    for (int i = 0; i < 2; i++) {
      int c = i * 256 + t;
      gload_lds16(A + (size_t)(m0 + (c >> 2)) * KD + k0 + (c & 3) * 8, (char*)Al + i * 4096 + w * 1024);
      gload_lds16(B + (size_t)(n0 + (c >> 2)) * KD + k0 + (c & 3) * 8, (char*)Bl + i * 4096 + w * 1024);
    }
    __syncthreads();
    bf16x8 af[4], bfr[4];
#pragma unroll
    for (int mi = 0; mi < 4; mi++) af[mi] = *(const bf16x8*)(Al + (wm + mi * 16 + lr) * 32 + lk8);
#pragma unroll
    for (int ni = 0; ni < 4; ni++) bfr[ni] = *(const bf16x8*)(Bl + (wn + ni * 16 + lr) * 32 + lk8);
#pragma unroll
    for (int mi = 0; mi < 4; mi++)
#pragma unroll
      for (int ni = 0; ni < 4; ni++)
        acc[mi][ni] = mfma16(af[mi], bfr[ni], acc[mi][ni]);
  }
#pragma unroll
  for (int mi = 0; mi < 4; mi++) {
#pragma unroll
    for (int ni = 0; ni < 4; ni++) {
#pragma unroll
      for (int r = 0; r < 4; r++) {
        int m = m0 + wm + mi * 16 + lg * 4 + r;
        int n = n0 + wn + ni * 16 + lr;
        out[(size_t)m * 1024 + n] = acc[mi][ni][r] + bo[n];
      }
    }
  }
}

// ---------------- differential flash attention ----------------
// P LDS layout: 16 rows x 72 u16 (144 B row), XOR swizzle s = ((row>>2)&3)<<5 on byte col.
// K LDS: 64 rows x 256 B, swizzle s = ((row&7)<<4).  V^T LDS: 64 rows x 128 B, same swizzle.
__device__ __forceinline__ void online_update(
    f32x4 s[4], bool diag, int q0w, int k0, int lr, int lg,
    float m[4], float lsum[4], f32x4 O[4], u16* Pw) {
#pragma unroll
  for (int r = 0; r < 4; r++) {
    float pv[4];
    float mx = -1e30f;
    if (diag) {
      int qg = q0w + lg * 4 + r;
#pragma unroll
      for (int ct = 0; ct < 4; ct++) {
        int kg = k0 + ct * 16 + lr;
        float sv = (kg <= qg) ? s[ct][r] * 0.125f : -1e30f;
        pv[ct] = sv;
        mx = fmaxf(mx, sv);
      }
    } else {
#pragma unroll
      for (int ct = 0; ct < 4; ct++) {
        float sv = s[ct][r] * 0.125f;
        pv[ct] = sv;
        mx = fmaxf(mx, sv);
      }
    }
#pragma unroll
    for (int d = 1; d < 16; d <<= 1) mx = fmaxf(mx, __shfl_xor(mx, d));
    float mn = fmaxf(m[r], mx);
    float f = __expf(m[r] - mn);
    float rs = 0.f;
#pragma unroll
    for (int ct = 0; ct < 4; ct++) {
      float p = __expf(pv[ct] - mn);
      pv[ct] = p;
      rs += p;
    }
#pragma unroll
    for (int d = 1; d < 16; d <<= 1) rs += __shfl_xor(rs, d);
    lsum[r] = lsum[r] * f + rs;
    m[r] = mn;
#pragma unroll
    for (int dt = 0; dt < 4; dt++) O[dt][r] *= f;
    int prow = lg * 4 + r;
#pragma unroll
    for (int ct = 0; ct < 4; ct++) {
      char* pb = (char*)Pw + prow * 144 + ((((unsigned)ct << 5) | ((unsigned)lr << 1)) ^ ((unsigned)lg << 5));
      *(u16*)pb = f2b(pv[ct]);
    }
  }
}

__device__ __forceinline__ void pv_acc(const u16* Pw, const u16* Vl, int lr, int lg, f32x4 O[4]) {
#pragma unroll
  for (int sl = 0; sl < 2; sl++) {
    const char* pb = (const char*)Pw + lr * 144 +
                     ((((unsigned)sl << 6) | ((unsigned)lg << 4)) ^ (((unsigned)(lr >> 2) & 3u) << 5));
    bf16x8 pf = *(const bf16x8*)pb;
#pragma unroll
    for (int dt = 0; dt < 4; dt++) {
      int vrow = dt * 16 + lr;
      const char* vb = (const char*)Vl + vrow * 128 +
                       ((((unsigned)sl << 6) | ((unsigned)lg << 4)) ^ (((unsigned)(lr & 7)) << 4));
      bf16x8 vf = *(const bf16x8*)vb;
      O[dt] = mfma16(pf, vf, O[dt]);
    }
  }
}

__global__ __launch_bounds__(256) void diff_attn(
    const u16* __restrict__ Q, const u16* __restrict__ Kk, const u16* __restrict__ V,
    const float* __restrict__ lamv, const float* __restrict__ hnw, u16* __restrict__ Aout) {
  __shared__ __align__(16) u16 Kl[64 * 128];     // 64 k-rows x 256 B, swizzled
  __shared__ __align__(16) u16 Vl[64 * 64];      // 64 d-rows x 128 B, swizzled
  __shared__ __align__(16) u16 Pl[4][16 * 72];   // per-wave P, 144 B rows, swizzled
  const int t = threadIdx.x, w = t >> 6, l = t & 63;
  const int lr = l & 15, lg = l >> 4, lk8 = lg * 8;
  const int bid = blockIdx.x;
  const int qt = 31 - (bid & 31);           // heavy blocks first
  const int h = (bid >> 5) & 15, b = bid >> 9;
  const int q0 = qt * 64;
  const size_t bh = (size_t)b * 16 + h;
  const u16* Qb = Q + bh * 2048 * 128;
  const char* Kbb = (const char*)(Kk + bh * 2048 * 128);
  const char* Vbb = (const char*)(V + bh * 64 * 2048);   // V^T: [64 d][2048 s]
  const float lam = lamv[h];
  bf16x8 qf[2][2];
#pragma unroll
  for (int hf = 0; hf < 2; hf++)
#pragma unroll
    for (int sl = 0; sl < 2; sl++)
      qf[hf][sl] = *(const bf16x8*)(Qb + (size_t)(q0 + w * 16 + lr) * 128 + hf * 64 + sl * 32 + lk8);
  f32x4 O1[4] = {}, O2[4] = {};
  float m1[4], l1[4], m2[4], l2[4];
#pragma unroll
  for (int r = 0; r < 4; r++) { m1[r] = -1e30f; l1[r] = 0.f; m2[r] = -1e30f; l2[r] = 0.f; }
  const int nkt = qt + 1;
  for (int kt = 0; kt < nkt; kt++) {
    const int k0 = kt * 64;
    __syncthreads();
    // K tile: 64 rows x 256 B, pre-swizzled global source -> linear LDS dest
    {
      const char* Kbase = Kbb + (size_t)k0 * 256;
#pragma unroll
      for (int i = 0; i < 4; i++) {
        int c = i * 256 + t;
        int row = c >> 4;
        unsigned cb = (unsigned)(c & 15) << 4;
        gload_lds16(Kbase + (size_t)row * 256 + (cb ^ (((unsigned)(row & 7)) << 4)),
                    (char*)Kl + i * 4096 + w * 1024);
      }
    }
    // V^T tile: 64 d-rows x 128 B from global stride 4096 B
    {
      const char* Vbase = Vbb + (size_t)k0 * 2;
#pragma unroll
      for (int i = 0; i < 2; i++) {
        int c = i * 256 + t;
        int row = c >> 3;
        unsigned cb = (unsigned)(c & 7) << 4;
        gload_lds16(Vbase + (size_t)row * 4096 + (cb ^ (((unsigned)(row & 7)) << 4)),
                    (char*)Vl + i * 4096 + w * 1024);
      }
    }
    __syncthreads();
    f32x4 s1[4] = {}, s2[4] = {};
#pragma unroll
    for (int ct = 0; ct < 4; ct++) {
      int krow = ct * 16 + lr;
      const char* kb = (const char*)Kl + krow * 256;
      unsigned sw = ((unsigned)(lr & 7)) << 4;
#pragma unroll
      for (int sl = 0; sl < 2; sl++) {
        bf16x8 kf1 = *(const bf16x8*)(kb + ((((unsigned)sl << 6) | ((unsigned)lg << 4)) ^ sw));
        bf16x8 kf2 = *(const bf16x8*)(kb + ((128u | ((unsigned)sl << 6) | ((unsigned)lg << 4)) ^ sw));
        s1[ct] = mfma16(qf[0][sl], kf1, s1[ct]);
        s2[ct] = mfma16(qf[1][sl], kf2, s2[ct]);
      }
    }
    bool diag = (kt == qt);
    online_update(s1, diag, q0 + w * 16, k0, lr, lg, m1, l1, O1, Pl[w]);
    pv_acc(Pl[w], Vl, lr, lg, O1);
    online_update(s2, diag, q0 + w * 16, k0, lr, lg, m2, l2, O2, Pl[w]);
    pv_acc(Pl[w], Vl, lr, lg, O2);
  }
  // epilogue: diff-combine, RMSNorm over hd=64, head weight, (1-lambda_init)=0.8
  float rr[4];
  f32x4 ov[4];
#pragma unroll
  for (int r = 0; r < 4; r++) {
    float i1 = 1.f / l1[r], i2 = lam / l2[r];
    float ss = 0.f;
#pragma unroll
    for (int dt = 0; dt < 4; dt++) {
      float o = O1[dt][r] * i1 - O2[dt][r] * i2;
      ov[dt][r] = o;
      ss += o * o;
    }
#pragma unroll
    for (int d = 1; d < 16; d <<= 1) ss += __shfl_xor(ss, d);
    rr[r] = rsqrtf(ss * (1.f / 64.f) + 1e-6f) * 0.8f;
  }
#pragma unroll
  for (int dt = 0; dt < 4; dt++) {
    float hw = hnw[h * 64 + dt * 16 + lr];
#pragma unroll
    for (int r = 0; r < 4; r++) {
      int qg = q0 + w * 16 + lg * 4 + r;
      Aout[((size_t)b * 2048 + qg) * 1024 + h * 64 + dt * 16 + lr] = f2b(ov[dt][r] * rr[r] * hw);
    }
  }
}

// ---------------- launch ----------------
extern "C" void kernel_launch(void* const* d_in, const int* in_sizes, int n_in,
                              void* d_out, int out_size, void* d_ws, size_t ws_size,
                              hipStream_t stream) {
  const float* x   = (const float*)d_in[0];
  const float* Wq  = (const float*)d_in[1];
  const float* bq  = (const float*)d_in[2];
  const float* Wk  = (const float*)d_in[3];
  const float* bk  = (const float*)d_in[4];
  const float* Wv  = (const float*)d_in[5];
  const float* bv  = (const float*)d_in[6];
  const float* Wo  = (const float*)d_in[7];
  const float* bo  = (const float*)d_in[8];
  const float* hnw = (const float*)d_in[9];
  const float* lq1 = (const float*)d_in[10];
  const float* lk1 = (const float*)d_in[11];
  const float* lq2 = (const float*)d_in[12];
  const float* lk2 = (const float*)d_in[13];
  float* out = (float*)d_out;
  char* ws = (char*)d_ws;

  u16*   x_bf  = (u16*)(ws);                 //  8,388,608 B  (4096x1024 bf16)
  u16*   wcat  = (u16*)(ws + 8388608);       // 10,485,760 B  (5120x1024 bf16: Wq|Wk|Wv)
  u16*   wo_bf = (u16*)(ws + 18874368);      //  2,097,152 B
  float* bcat  = (float*)(ws + 20971520);    //     20,480 B
  float* lam   = (float*)(ws + 20992000);    //         64 B
  u16*   q_r   = (u16*)(ws + 20992064);      // 16,777,216 B  (B,H,S,128)
  u16*   k_r   = (u16*)(ws + 37769280);      // 16,777,216 B
  u16*   v_t   = (u16*)(ws + 54546496);      //  8,388,608 B  (B,H,64,S)  V transposed
  u16*   a_out = (u16*)(ws + 62935104);      //  8,388,608 B  (4096x1024 bf16)

  cvt_k<<<4096, 256, 0, stream>>>(x, x_bf, 4194304);
  cvt_k<<<2048, 256, 0, stream>>>(Wq, wcat, 2097152);
  cvt_k<<<2048, 256, 0, stream>>>(Wk, wcat + 2097152, 2097152);
  cvt_k<<<1024, 256, 0, stream>>>(Wv, wcat + 4194304, 1048576);
  cvt_k<<<1024, 256, 0, stream>>>(Wo, wo_bf, 1048576);
  bcat_k<<<20, 256, 0, stream>>>(bq, bk, bv, bcat);
  lam_k<<<1, 64, 0, stream>>>(lq1, lk1, lq2, lk2, lam);
  gemm_qkv<<<dim3(40, 32), 256, 0, stream>>>(x_bf, wcat, bcat, q_r, k_r, v_t);
  rope_k<<<8192, 256, 0, stream>>>(q_r, k_r);
  diff_attn<<<1024, 256, 0, stream>>>(q_r, k_r, v_t, lam, hnw, a_out);
  gemm_wo<<<dim3(8, 32), 256, 0, stream>>>(a_out, wo_bf, bo, out);
}

// Round 4
// 358.016 us; speedup vs baseline: 1.5279x; 1.4045x over previous
//
#include <hip/hip_runtime.h>
#include <stdint.h>

typedef __attribute__((ext_vector_type(8))) short bf16x8;   // 8 bf16 in 4 VGPRs (guide §3)
typedef __attribute__((ext_vector_type(4))) float f32x4;
typedef __attribute__((ext_vector_type(4))) unsigned short u16x4;
typedef unsigned short u16;

__device__ __forceinline__ u16 f2b(float f) {               // round-half-up f32->bf16 (2 VALU)
  uint32_t u = __builtin_bit_cast(uint32_t, f);
  return (u16)((u + 0x8000u) >> 16);
}
__device__ __forceinline__ float b2f(u16 v) {
  uint32_t u = ((uint32_t)v) << 16;
  return __builtin_bit_cast(float, u);
}
__device__ __forceinline__ f32x4 mfma16(bf16x8 a, bf16x8 b, f32x4 c) {
  return __builtin_amdgcn_mfma_f32_16x16x32_bf16(a, b, c, 0, 0, 0);
}
__device__ __forceinline__ void gload_lds16(const void* g, void* l) {
  __builtin_amdgcn_global_load_lds((const __attribute__((address_space(1))) unsigned int*)g,
                                   (__attribute__((address_space(3))) unsigned int*)l, 16, 0, 0);
}

// ---------------- conversion / small kernels ----------------
__global__ __launch_bounds__(256) void cvt_k(const float* __restrict__ src, u16* __restrict__ dst, int n) {
  int i = (blockIdx.x * 256 + threadIdx.x) * 4;
  if (i >= n) return;
  float4 v = *(const float4*)(src + i);
  u16x4 o; o[0] = f2b(v.x); o[1] = f2b(v.y); o[2] = f2b(v.z); o[3] = f2b(v.w);
  *(u16x4*)(dst + i) = o;
}

__global__ __launch_bounds__(256) void bcat_k(const float* __restrict__ bq, const float* __restrict__ bk,
                                              const float* __restrict__ bv, float* __restrict__ bcat) {
  int i = blockIdx.x * 256 + threadIdx.x;   // 5120 total
  bcat[i] = (i < 2048) ? bq[i] : ((i < 4096) ? bk[i - 2048] : bv[i - 4096]);
}

__global__ void lam_k(const float* __restrict__ lq1, const float* __restrict__ lk1,
                      const float* __restrict__ lq2, const float* __restrict__ lk2,
                      float* __restrict__ lam) {
  int h = threadIdx.x;
  if (h < 16) {
    float d1 = 0.f, d2 = 0.f;
    for (int i = 0; i < 64; i++) {
      d1 += lq1[h * 64 + i] * lk1[h * 64 + i];
      d2 += lq2[h * 64 + i] * lk2[h * 64 + i];
    }
    lam[h] = 0.2f + __expf(d1) - __expf(d2);  // LAMBDA_INIT = 0.2
  }
}

// In-place RoPE on q and k, layout (B*H*S) x 128, both 64-dim halves rotated.
// q additionally folded with the 1/sqrt(hd)=0.125 attention scale (exact exponent shift).
__global__ __launch_bounds__(256) void rope_k(u16* __restrict__ q, u16* __restrict__ k) {
  int u = blockIdx.x * 256 + threadIdx.x;   // 65536 rows * 32 pairs
  int i = u & 31;
  int row = u >> 5;
  int s = row & 2047;
  float inv = __expf(-9.210340371976184f * (float)i * (1.f / 32.f)); // 10000^(-i/32)
  float ang = (float)s * inv;
  float c = cosf(ang), sn = sinf(ang);      // accurate range reduction for large args
  size_t base = (size_t)row * 128;
#pragma unroll
  for (int hf = 0; hf < 2; hf++) {
    size_t p = base + hf * 64 + i;
    float a = b2f(q[p]), b = b2f(q[p + 32]);
    q[p] = f2b((a * c - b * sn) * 0.125f);
    q[p + 32] = f2b((a * sn + b * c) * 0.125f);
    float ka = b2f(k[p]), kb = b2f(k[p + 32]);
    k[p] = f2b(ka * c - kb * sn);
    k[p + 32] = f2b(ka * sn + kb * c);
  }
}

// ---------------- GEMM (m97-style 128x128 tile, BK=32, 4 waves) ----------------
#define KD 1024

__global__ __launch_bounds__(256) void gemm_qkv(
    const u16* __restrict__ A, const u16* __restrict__ B, const float* __restrict__ bcat,
    u16* __restrict__ qout, u16* __restrict__ kout, u16* __restrict__ vout) {
  __shared__ __align__(16) u16 Al[128 * 32];
  __shared__ __align__(16) u16 Bl[128 * 32];
  const int t = threadIdx.x;
  const int w = t >> 6;
  const int l = t & 63;
  const int lr = l & 15, lg = l >> 4, lk8 = lg * 8;
  const int wm = (w >> 1) * 64, wn = (w & 1) * 64;
  const int n0 = blockIdx.x * 128, m0 = blockIdx.y * 128;
  f32x4 acc[4][4] = {};
  for (int k0 = 0; k0 < KD; k0 += 32) {
    __syncthreads();
#pragma unroll
    for (int i = 0; i < 2; i++) {
      int c = i * 256 + t;
      gload_lds16(A + (size_t)(m0 + (c >> 2)) * KD + k0 + (c & 3) * 8, (char*)Al + i * 4096 + w * 1024);
      gload_lds16(B + (size_t)(n0 + (c >> 2)) * KD + k0 + (c & 3) * 8, (char*)Bl + i * 4096 + w * 1024);
    }
    __syncthreads();
    bf16x8 af[4], bfr[4];
#pragma unroll
    for (int mi = 0; mi < 4; mi++) af[mi] = *(const bf16x8*)(Al + (wm + mi * 16 + lr) * 32 + lk8);
#pragma unroll
    for (int ni = 0; ni < 4; ni++) bfr[ni] = *(const bf16x8*)(Bl + (wn + ni * 16 + lr) * 32 + lk8);
#pragma unroll
    for (int mi = 0; mi < 4; mi++)
#pragma unroll
      for (int ni = 0; ni < 4; ni++)
        acc[mi][ni] = mfma16(af[mi], bfr[ni], acc[mi][ni]);
  }
  // epilogue: +bias, bf16, scatter into (B,H,S,·); V goes out TRANSPOSED: [b][h][d][S]
#pragma unroll
  for (int mi = 0; mi < 4; mi++) {
#pragma unroll
    for (int ni = 0; ni < 4; ni++) {
      int n = n0 + wn + ni * 16 + lr;
      int mbase = m0 + wm + mi * 16 + lg * 4;
      float bc = bcat[n];
      if (n >= 4096) {            // V: 4 consecutive s rows -> one 8B store
        int nv = n - 4096, h = nv >> 6, d = nv & 63;
        int b = mbase >> 11, s = mbase & 2047;
        u16x4 pk;
#pragma unroll
        for (int r = 0; r < 4; r++) pk[r] = f2b(acc[mi][ni][r] + bc);
        *(u16x4*)(vout + ((size_t)(b * 16 + h) * 64 + d) * 2048 + s) = pk;
      } else {
#pragma unroll
        for (int r = 0; r < 4; r++) {
          int m = mbase + r;
          float v = acc[mi][ni][r] + bc;
          int b = m >> 11, s = m & 2047;
          u16 bv = f2b(v);
          if (n < 2048) {
            int h = n >> 7, d = n & 127;
            qout[((size_t)(b * 16 + h) * 2048 + s) * 128 + d] = bv;
          } else {
            int nk = n - 2048, h = nk >> 7, d = nk & 127;
            kout[((size_t)(b * 16 + h) * 2048 + s) * 128 + d] = bv;
          }
        }
      }
    }
  }
}

__global__ __launch_bounds__(256) void gemm_wo(
    const u16* __restrict__ A, const u16* __restrict__ B, const float* __restrict__ bo,
    float* __restrict__ out) {
  __shared__ __align__(16) u16 Al[128 * 32];
  __shared__ __align__(16) u16 Bl[128 * 32];
  const int t = threadIdx.x;
  const int w = t >> 6;
  const int l = t & 63;
  const int lr = l & 15, lg = l >> 4, lk8 = lg * 8;
  const int wm = (w >> 1) * 64, wn = (w & 1) * 64;
  const int n0 = blockIdx.x * 128, m0 = blockIdx.y * 128;
  f32x4 acc[4][4] = {};
  for (int k0 = 0; k0 < KD; k0 += 32) {
    __syncthreads();
#pragma unroll
    for (int i = 0; i < 2; i++) {
      int c = i * 256 + t;
      gload_lds16(A + (size_t)(m0 + (c >> 2)) * KD + k0 + (c & 3) * 8, (char*)Al + i * 4096 + w * 1024);
      gload_lds16(B + (size_t)(n0 + (c >> 2)) * KD + k0 + (c & 3) * 8, (char*)Bl + i * 4096 + w * 1024);
    }
    __syncthreads();
    bf16x8 af[4], bfr[4];
#pragma unroll
    for (int mi = 0; mi < 4; mi++) af[mi] = *(const bf16x8*)(Al + (wm + mi * 16 + lr) * 32 + lk8);
#pragma unroll
    for (int ni = 0; ni < 4; ni++) bfr[ni] = *(const bf16x8*)(Bl + (wn + ni * 16 + lr) * 32 + lk8);
#pragma unroll
    for (int mi = 0; mi < 4; mi++)
#pragma unroll
      for (int ni = 0; ni < 4; ni++)
        acc[mi][ni] = mfma16(af[mi], bfr[ni], acc[mi][ni]);
  }
#pragma unroll
  for (int mi = 0; mi < 4; mi++) {
#pragma unroll
    for (int ni = 0; ni < 4; ni++) {
#pragma unroll
      for (int r = 0; r < 4; r++) {
        int m = m0 + wm + mi * 16 + lg * 4 + r;
        int n = n0 + wn + ni * 16 + lr;
        out[(size_t)m * 1024 + n] = acc[mi][ni][r] + bo[n];
      }
    }
  }
}

// ---------------- differential flash attention ----------------
// P LDS layout: 16 rows x 144 B, XOR swizzle (row>>2)<<5 on byte col.
// K LDS: 64 rows x 256 B, swizzle ((row&7)<<4).  V^T LDS: 64 rows x 128 B, same swizzle.
// Q pre-scaled by 0.125 in rope_k, so raw MFMA output is the scaled score.
__device__ __forceinline__ void online_update(
    f32x4 s[4], bool diag, int q0w, int k0, int lr, int lg,
    float m[4], float lsum[4], f32x4 O[4], u16* Pw) {
#pragma unroll
  for (int r = 0; r < 4; r++) {
    float pv[4];
    float mx = -1e30f;
    if (diag) {
      int qg = q0w + lg * 4 + r;
#pragma unroll
      for (int ct = 0; ct < 4; ct++) {
        int kg = k0 + ct * 16 + lr;
        float sv = (kg <= qg) ? s[ct][r] : -1e30f;
        pv[ct] = sv;
        mx = fmaxf(mx, sv);
      }
    } else {
#pragma unroll
      for (int ct = 0; ct < 4; ct++) {
        pv[ct] = s[ct][r];
        mx = fmaxf(mx, pv[ct]);
      }
    }
#pragma unroll
    for (int d = 1; d < 16; d <<= 1) mx = fmaxf(mx, __shfl_xor(mx, d));
    float mn = fmaxf(m[r], mx);
    float f = __expf(m[r] - mn);
    float rs = 0.f;
#pragma unroll
    for (int ct = 0; ct < 4; ct++) {
      float p = __expf(pv[ct] - mn);
      pv[ct] = p;
      rs += p;
    }
#pragma unroll
    for (int d = 1; d < 16; d <<= 1) rs += __shfl_xor(rs, d);
    lsum[r] = lsum[r] * f + rs;
    m[r] = mn;
#pragma unroll
    for (int dt = 0; dt < 4; dt++) O[dt][r] *= f;
    int prow = lg * 4 + r;
#pragma unroll
    for (int ct = 0; ct < 4; ct++) {
      char* pb = (char*)Pw + prow * 144 + ((((unsigned)ct << 5) | ((unsigned)lr << 1)) ^ ((unsigned)lg << 5));
      *(u16*)pb = f2b(pv[ct]);
    }
  }
}

__device__ __forceinline__ void pv_acc(const u16* Pw, const u16* Vl, int lr, int lg, f32x4 O[4]) {
#pragma unroll
  for (int sl = 0; sl < 2; sl++) {
    const char* pb = (const char*)Pw + lr * 144 +
                     ((((unsigned)sl << 6) | ((unsigned)lg << 4)) ^ (((unsigned)(lr >> 2) & 3u) << 5));
    bf16x8 pf = *(const bf16x8*)pb;
#pragma unroll
    for (int dt = 0; dt < 4; dt++) {
      int vrow = dt * 16 + lr;
      const char* vb = (const char*)Vl + vrow * 128 +
                       ((((unsigned)sl << 6) | ((unsigned)lg << 4)) ^ (((unsigned)(lr & 7)) << 4));
      bf16x8 vf = *(const bf16x8*)vb;
      O[dt] = mfma16(pf, vf, O[dt]);
    }
  }
}

__global__ __launch_bounds__(256) void diff_attn(
    const u16* __restrict__ Q, const u16* __restrict__ Kk, const u16* __restrict__ V,
    const float* __restrict__ lamv, const float* __restrict__ hnw, u16* __restrict__ Aout) {
  __shared__ __align__(16) u16 Kl[2][64 * 128];     // double-buffered K tile (swizzled)
  __shared__ __align__(16) u16 Vl[2][64 * 64];      // double-buffered V^T tile (swizzled)
  __shared__ __align__(16) u16 Pl[4][2][16 * 72];   // per-wave P, two buffers (s1/s2)
  const int t = threadIdx.x, w = t >> 6, l = t & 63;
  const int lr = l & 15, lg = l >> 4, lk8 = lg * 8;
  const int bid = blockIdx.x;
  const int pr = bid & 15;                  // pair index: q-tiles (pr, 31-pr) => 33 k-iters/block
  const int h = (bid >> 4) & 15, b = bid >> 8;
  const size_t bh = (size_t)b * 16 + h;
  const u16* Qb = Q + bh * 2048 * 128;
  const char* Kbb = (const char*)(Kk + bh * 2048 * 128);
  const char* Vbb = (const char*)(V + bh * 64 * 2048);   // V^T: [64 d][2048 s]
  const float lam = lamv[h];
  float hw4[4];
#pragma unroll
  for (int dt = 0; dt < 4; dt++) hw4[dt] = hnw[h * 64 + dt * 16 + lr];

  auto stage = [&](int buf, int k0) {
    const char* Kbase = Kbb + (size_t)k0 * 256;
#pragma unroll
    for (int i = 0; i < 4; i++) {
      int c = i * 256 + t;
      int row = c >> 4;
      unsigned cb = (unsigned)(c & 15) << 4;
      gload_lds16(Kbase + (size_t)row * 256 + (cb ^ (((unsigned)(row & 7)) << 4)),
                  (char*)Kl[buf] + i * 4096 + w * 1024);
    }
    const char* Vbase = Vbb + (size_t)k0 * 2;
#pragma unroll
    for (int i = 0; i < 2; i++) {
      int c = i * 256 + t;
      int row = c >> 3;
      unsigned cb = (unsigned)(c & 7) << 4;
      gload_lds16(Vbase + (size_t)row * 4096 + (cb ^ (((unsigned)(row & 7)) << 4)),
                  (char*)Vl[buf] + i * 4096 + w * 1024);
    }
  };

  for (int half = 0; half < 2; half++) {
    const int qt = half ? (31 - pr) : pr;
    const int q0 = qt * 64;
    bf16x8 qf[2][2];
#pragma unroll
    for (int hf = 0; hf < 2; hf++)
#pragma unroll
      for (int sl = 0; sl < 2; sl++)
        qf[hf][sl] = *(const bf16x8*)(Qb + (size_t)(q0 + w * 16 + lr) * 128 + hf * 64 + sl * 32 + lk8);
    f32x4 O1[4] = {}, O2[4] = {};
    float m1[4], l1[4], m2[4], l2[4];
#pragma unroll
    for (int r = 0; r < 4; r++) { m1[r] = -1e30f; l1[r] = 0.f; m2[r] = -1e30f; l2[r] = 0.f; }
    const int nkt = qt + 1;
    int cur = 0;
    stage(0, 0);
    __syncthreads();
    for (int kt = 0; kt < nkt; kt++) {
      if (kt + 1 < nkt) stage(cur ^ 1, (kt + 1) << 6);   // depth-1 prefetch overlaps compute
      const int k0 = kt << 6;
      f32x4 s1[4] = {}, s2[4] = {};
      const u16* Kc = Kl[cur];
#pragma unroll
      for (int ct = 0; ct < 4; ct++) {
        int krow = ct * 16 + lr;
        const char* kb = (const char*)Kc + krow * 256;
        unsigned sw = ((unsigned)(lr & 7)) << 4;
#pragma unroll
        for (int sl = 0; sl < 2; sl++) {
          bf16x8 kf1 = *(const bf16x8*)(kb + ((((unsigned)sl << 6) | ((unsigned)lg << 4)) ^ sw));
          bf16x8 kf2 = *(const bf16x8*)(kb + ((128u | ((unsigned)sl << 6) | ((unsigned)lg << 4)) ^ sw));
          s1[ct] = mfma16(qf[0][sl], kf1, s1[ct]);
          s2[ct] = mfma16(qf[1][sl], kf2, s2[ct]);
        }
      }
      bool diag = (kt == nkt - 1);
      online_update(s1, diag, q0 + w * 16, k0, lr, lg, m1, l1, O1, Pl[w][0]);
      online_update(s2, diag, q0 + w * 16, k0, lr, lg, m2, l2, O2, Pl[w][1]);
      pv_acc(Pl[w][0], Vl[cur], lr, lg, O1);
      pv_acc(Pl[w][1], Vl[cur], lr, lg, O2);
      __syncthreads();          // drains prefetch (vmcnt) + protects cur buffer reuse
      cur ^= 1;
    }
    // epilogue: diff-combine, RMSNorm over hd=64, head weight, (1-lambda_init)=0.8
    float rr[4];
    f32x4 ov[4];
#pragma unroll
    for (int r = 0; r < 4; r++) {
      float i1 = 1.f / l1[r], i2 = lam / l2[r];
      float ss = 0.f;
#pragma unroll
      for (int dt = 0; dt < 4; dt++) {
        float o = O1[dt][r] * i1 - O2[dt][r] * i2;
        ov[dt][r] = o;
        ss += o * o;
      }
#pragma unroll
      for (int d = 1; d < 16; d <<= 1) ss += __shfl_xor(ss, d);
      rr[r] = rsqrtf(ss * (1.f / 64.f) + 1e-6f) * 0.8f;
    }
#pragma unroll
    for (int dt = 0; dt < 4; dt++) {
#pragma unroll
      for (int r = 0; r < 4; r++) {
        int qg = q0 + w * 16 + lg * 4 + r;
        Aout[((size_t)b * 2048 + qg) * 1024 + h * 64 + dt * 16 + lr] = f2b(ov[dt][r] * rr[r] * hw4[dt]);
      }
    }
  }
}

// ---------------- launch ----------------
extern "C" void kernel_launch(void* const* d_in, const int* in_sizes, int n_in,
                              void* d_out, int out_size, void* d_ws, size_t ws_size,
                              hipStream_t stream) {
  const float* x   = (const float*)d_in[0];
  const float* Wq  = (const float*)d_in[1];
  const float* bq  = (const float*)d_in[2];
  const float* Wk  = (const float*)d_in[3];
  const float* bk  = (const float*)d_in[4];
  const float* Wv  = (const float*)d_in[5];
  const float* bv  = (const float*)d_in[6];
  const float* Wo  = (const float*)d_in[7];
  const float* bo  = (const float*)d_in[8];
  const float* hnw = (const float*)d_in[9];
  const float* lq1 = (const float*)d_in[10];
  const float* lk1 = (const float*)d_in[11];
  const float* lq2 = (const float*)d_in[12];
  const float* lk2 = (const float*)d_in[13];
  float* out = (float*)d_out;
  char* ws = (char*)d_ws;

  u16*   x_bf  = (u16*)(ws);                 //  8,388,608 B  (4096x1024 bf16)
  u16*   wcat  = (u16*)(ws + 8388608);       // 10,485,760 B  (5120x1024 bf16: Wq|Wk|Wv)
  u16*   wo_bf = (u16*)(ws + 18874368);      //  2,097,152 B
  float* bcat  = (float*)(ws + 20971520);    //     20,480 B
  float* lam   = (float*)(ws + 20992000);    //         64 B
  u16*   q_r   = (u16*)(ws + 20992064);      // 16,777,216 B  (B,H,S,128)
  u16*   k_r   = (u16*)(ws + 37769280);      // 16,777,216 B
  u16*   v_t   = (u16*)(ws + 54546496);      //  8,388,608 B  (B,H,64,S)  V transposed
  u16*   a_out = (u16*)(ws + 62935104);      //  8,388,608 B  (4096x1024 bf16)

  cvt_k<<<4096, 256, 0, stream>>>(x, x_bf, 4194304);
  cvt_k<<<2048, 256, 0, stream>>>(Wq, wcat, 2097152);
  cvt_k<<<2048, 256, 0, stream>>>(Wk, wcat + 2097152, 2097152);
  cvt_k<<<1024, 256, 0, stream>>>(Wv, wcat + 4194304, 1048576);
  cvt_k<<<1024, 256, 0, stream>>>(Wo, wo_bf, 1048576);
  bcat_k<<<20, 256, 0, stream>>>(bq, bk, bv, bcat);
  lam_k<<<1, 64, 0, stream>>>(lq1, lk1, lq2, lk2, lam);
  gemm_qkv<<<dim3(40, 32), 256, 0, stream>>>(x_bf, wcat, bcat, q_r, k_r, v_t);
  rope_k<<<8192, 256, 0, stream>>>(q_r, k_r);
  diff_attn<<<512, 256, 0, stream>>>(q_r, k_r, v_t, lam, hnw, a_out);
  gemm_wo<<<dim3(8, 32), 256, 0, stream>>>(a_out, wo_bf, bo, out);
}

// Round 6
// 321.810 us; speedup vs baseline: 1.6998x; 1.1125x over previous
//
#include <hip/hip_runtime.h>
#include <stdint.h>

typedef __attribute__((ext_vector_type(8))) short bf16x8;   // 8 bf16 in 4 VGPRs
typedef __attribute__((ext_vector_type(4))) float f32x4;
typedef __attribute__((ext_vector_type(4))) unsigned short u16x4;
typedef unsigned short u16;

__device__ __forceinline__ u16 f2b(float f) {               // round-half-up f32->bf16
  uint32_t u = __builtin_bit_cast(uint32_t, f);
  return (u16)((u + 0x8000u) >> 16);
}
__device__ __forceinline__ float b2f(u16 v) {
  uint32_t u = ((uint32_t)v) << 16;
  return __builtin_bit_cast(float, u);
}
__device__ __forceinline__ f32x4 mfma16(bf16x8 a, bf16x8 b, f32x4 c) {
  return __builtin_amdgcn_mfma_f32_16x16x32_bf16(a, b, c, 0, 0, 0);
}
__device__ __forceinline__ void gload_lds16(const void* g, void* l) {
  __builtin_amdgcn_global_load_lds((const __attribute__((address_space(1))) unsigned int*)g,
                                   (__attribute__((address_space(3))) unsigned int*)l, 16, 0, 0);
}

// ---------------- conversion / small kernels ----------------
__global__ __launch_bounds__(256) void cvt_k(const float* __restrict__ src, u16* __restrict__ dst, int n) {
  int i = (blockIdx.x * 256 + threadIdx.x) * 4;
  if (i >= n) return;
  float4 v = *(const float4*)(src + i);
  u16x4 o; o[0] = f2b(v.x); o[1] = f2b(v.y); o[2] = f2b(v.z); o[3] = f2b(v.w);
  *(u16x4*)(dst + i) = o;
}

__global__ __launch_bounds__(256) void bcat_k(const float* __restrict__ bq, const float* __restrict__ bk,
                                              const float* __restrict__ bv, float* __restrict__ bcat) {
  int i = blockIdx.x * 256 + threadIdx.x;   // 5120 total
  bcat[i] = (i < 2048) ? bq[i] : ((i < 4096) ? bk[i - 2048] : bv[i - 4096]);
}

__global__ void lam_k(const float* __restrict__ lq1, const float* __restrict__ lk1,
                      const float* __restrict__ lq2, const float* __restrict__ lk2,
                      float* __restrict__ lam) {
  int h = threadIdx.x;
  if (h < 16) {
    float d1 = 0.f, d2 = 0.f;
    for (int i = 0; i < 64; i++) {
      d1 += lq1[h * 64 + i] * lk1[h * 64 + i];
      d2 += lq2[h * 64 + i] * lk2[h * 64 + i];
    }
    lam[h] = 0.2f + __expf(d1) - __expf(d2);  // LAMBDA_INIT = 0.2
  }
}

// In-place RoPE on q and k; q folded with 1/sqrt(hd)=0.125 attention scale.
__global__ __launch_bounds__(256) void rope_k(u16* __restrict__ q, u16* __restrict__ k) {
  int u = blockIdx.x * 256 + threadIdx.x;   // 65536 rows * 32 pairs
  int i = u & 31;
  int row = u >> 5;
  int s = row & 2047;
  float inv = __expf(-9.210340371976184f * (float)i * (1.f / 32.f)); // 10000^(-i/32)
  float ang = (float)s * inv;
  float c = cosf(ang), sn = sinf(ang);
  size_t base = (size_t)row * 128;
#pragma unroll
  for (int hf = 0; hf < 2; hf++) {
    size_t p = base + hf * 64 + i;
    float a = b2f(q[p]), b = b2f(q[p + 32]);
    q[p] = f2b((a * c - b * sn) * 0.125f);
    q[p + 32] = f2b((a * sn + b * c) * 0.125f);
    float ka = b2f(k[p]), kb = b2f(k[p + 32]);
    k[p] = f2b(ka * c - kb * sn);
    k[p + 32] = f2b(ka * sn + kb * c);
  }
}

// ---------------- GEMM (m97-style 128x128 tile, BK=32, 4 waves) ----------------
#define KD 1024

__global__ __launch_bounds__(256) void gemm_qkv(
    const u16* __restrict__ A, const u16* __restrict__ B, const float* __restrict__ bcat,
    u16* __restrict__ qout, u16* __restrict__ kout, u16* __restrict__ vout) {
  __shared__ __align__(16) u16 Al[128 * 32];
  __shared__ __align__(16) u16 Bl[128 * 32];
  const int t = threadIdx.x;
  const int w = t >> 6;
  const int l = t & 63;
  const int lr = l & 15, lg = l >> 4, lk8 = lg * 8;
  const int wm = (w >> 1) * 64, wn = (w & 1) * 64;
  const int n0 = blockIdx.x * 128, m0 = blockIdx.y * 128;
  f32x4 acc[4][4] = {};
  for (int k0 = 0; k0 < KD; k0 += 32) {
    __syncthreads();
#pragma unroll
    for (int i = 0; i < 2; i++) {
      int c = i * 256 + t;
      gload_lds16(A + (size_t)(m0 + (c >> 2)) * KD + k0 + (c & 3) * 8, (char*)Al + i * 4096 + w * 1024);
      gload_lds16(B + (size_t)(n0 + (c >> 2)) * KD + k0 + (c & 3) * 8, (char*)Bl + i * 4096 + w * 1024);
    }
    __syncthreads();
    bf16x8 af[4], bfr[4];
#pragma unroll
    for (int mi = 0; mi < 4; mi++) af[mi] = *(const bf16x8*)(Al + (wm + mi * 16 + lr) * 32 + lk8);
#pragma unroll
    for (int ni = 0; ni < 4; ni++) bfr[ni] = *(const bf16x8*)(Bl + (wn + ni * 16 + lr) * 32 + lk8);
#pragma unroll
    for (int mi = 0; mi < 4; mi++)
#pragma unroll
      for (int ni = 0; ni < 4; ni++)
        acc[mi][ni] = mfma16(af[mi], bfr[ni], acc[mi][ni]);
  }
  // epilogue: +bias, bf16, scatter; V goes out TRANSPOSED: [b][h][d][S]
#pragma unroll
  for (int mi = 0; mi < 4; mi++) {
#pragma unroll
    for (int ni = 0; ni < 4; ni++) {
      int n = n0 + wn + ni * 16 + lr;
      int mbase = m0 + wm + mi * 16 + lg * 4;
      float bc = bcat[n];
      if (n >= 4096) {
        int nv = n - 4096, h = nv >> 6, d = nv & 63;
        int b = mbase >> 11, s = mbase & 2047;
        u16x4 pk;
#pragma unroll
        for (int r = 0; r < 4; r++) pk[r] = f2b(acc[mi][ni][r] + bc);
        *(u16x4*)(vout + ((size_t)(b * 16 + h) * 64 + d) * 2048 + s) = pk;
      } else {
#pragma unroll
        for (int r = 0; r < 4; r++) {
          int m = mbase + r;
          float v = acc[mi][ni][r] + bc;
          int b = m >> 11, s = m & 2047;
          u16 bv = f2b(v);
          if (n < 2048) {
            int h = n >> 7, d = n & 127;
            qout[((size_t)(b * 16 + h) * 2048 + s) * 128 + d] = bv;
          } else {
            int nk = n - 2048, h = nk >> 7, d = nk & 127;
            kout[((size_t)(b * 16 + h) * 2048 + s) * 128 + d] = bv;
          }
        }
      }
    }
  }
}

__global__ __launch_bounds__(256) void gemm_wo(
    const u16* __restrict__ A, const u16* __restrict__ B, const float* __restrict__ bo,
    float* __restrict__ out) {
  __shared__ __align__(16) u16 Al[128 * 32];
  __shared__ __align__(16) u16 Bl[128 * 32];
  const int t = threadIdx.x;
  const int w = t >> 6;
  const int l = t & 63;
  const int lr = l & 15, lg = l >> 4, lk8 = lg * 8;
  const int wm = (w >> 1) * 64, wn = (w & 1) * 64;
  const int n0 = blockIdx.x * 128, m0 = blockIdx.y * 128;
  f32x4 acc[4][4] = {};
  for (int k0 = 0; k0 < KD; k0 += 32) {
    __syncthreads();
#pragma unroll
    for (int i = 0; i < 2; i++) {
      int c = i * 256 + t;
      gload_lds16(A + (size_t)(m0 + (c >> 2)) * KD + k0 + (c & 3) * 8, (char*)Al + i * 4096 + w * 1024);
      gload_lds16(B + (size_t)(n0 + (c >> 2)) * KD + k0 + (c & 3) * 8, (char*)Bl + i * 4096 + w * 1024);
    }
    __syncthreads();
    bf16x8 af[4], bfr[4];
#pragma unroll
    for (int mi = 0; mi < 4; mi++) af[mi] = *(const bf16x8*)(Al + (wm + mi * 16 + lr) * 32 + lk8);
#pragma unroll
    for (int ni = 0; ni < 4; ni++) bfr[ni] = *(const bf16x8*)(Bl + (wn + ni * 16 + lr) * 32 + lk8);
#pragma unroll
    for (int mi = 0; mi < 4; mi++)
#pragma unroll
      for (int ni = 0; ni < 4; ni++)
        acc[mi][ni] = mfma16(af[mi], bfr[ni], acc[mi][ni]);
  }
#pragma unroll
  for (int mi = 0; mi < 4; mi++) {
#pragma unroll
    for (int ni = 0; ni < 4; ni++) {
#pragma unroll
      for (int r = 0; r < 4; r++) {
        int m = m0 + wm + mi * 16 + lg * 4 + r;
        int n = n0 + wn + ni * 16 + lr;
        out[(size_t)m * 1024 + n] = acc[mi][ni][r] + bo[n];
      }
    }
  }
}

// ---------------- differential flash attention (fixed-shift softmax) ----------------
// 2 waves/block, QBLK=32 (16 q-rows/wave), KVB=32, q-tile pairs (pr, 63-pr) => 65 iters.
// No running max/rescale: p = exp(s) directly (scores bounded; diag keeps l >= 1).
// l = sum_k p via ones-column MFMA. P packed (p1 lo | p2 hi) u32, explicit integer pack.
// K LDS: 32 rows x 256 B, XOR swizzle ((row&7)<<4), dbuf + depth-1 prefetch. V read direct (L2).
#define KVB 32

__global__ __launch_bounds__(128) void diff_attn(
    const u16* __restrict__ Q, const u16* __restrict__ Kk, const u16* __restrict__ V,
    const float* __restrict__ lamv, const float* __restrict__ hnw, u16* __restrict__ Aout) {
  __shared__ __align__(16) u16 Kl[2][KVB * 128];   // 2 x 8 KB swizzled
  __shared__ __align__(16) char Pl[2][16 * 144];   // per-wave packed P12
  const int t = threadIdx.x, w = t >> 6, l = t & 63;
  const int lr = l & 15, lg = l >> 4;
  // XCD-aware bijective swizzle: 1024 blocks, 8 XCDs -> 128 contiguous per XCD
  const int bid = (blockIdx.x & 7) * 128 + (blockIdx.x >> 3);
  const int pr = bid & 31;                  // pair: q-tiles (pr, 63-pr) => 65 k-iters total
  const int h = (bid >> 5) & 15, b = bid >> 9;
  const size_t bh = (size_t)b * 16 + h;
  const u16* Qb = Q + bh * 2048 * 128;
  const char* Kbb = (const char*)(Kk + bh * 2048 * 128);
  const char* Vbb = (const char*)(V + bh * 64 * 2048);   // V^T: [64 d][2048 s]
  const float lam = lamv[h];
  float hw4[4];
#pragma unroll
  for (int dt = 0; dt < 4; dt++) hw4[dt] = hnw[h * 64 + dt * 16 + lr];
  const bf16x8 ones = {(short)0x3F80, (short)0x3F80, (short)0x3F80, (short)0x3F80,
                       (short)0x3F80, (short)0x3F80, (short)0x3F80, (short)0x3F80};

  auto stage = [&](int buf, int k0) {
    const char* Kbase = Kbb + (size_t)k0 * 256;
#pragma unroll
    for (int i = 0; i < 4; i++) {
      int c = i * 128 + t;
      int row = c >> 4;
      unsigned cb = (unsigned)(c & 15) << 4;
      gload_lds16(Kbase + (size_t)row * 256 + (cb ^ (((unsigned)(row & 7)) << 4)),
                  (char*)Kl[buf] + i * 2048 + w * 1024);
    }
  };

  char* Pw = Pl[w];

  for (int half = 0; half < 2; half++) {
    const int qt = half ? (63 - pr) : pr;
    const int q0 = qt * 32;
    bf16x8 qf[2][2];
#pragma unroll
    for (int hf = 0; hf < 2; hf++)
#pragma unroll
      for (int ds = 0; ds < 2; ds++)
        qf[hf][ds] = *(const bf16x8*)(Qb + (size_t)(q0 + w * 16 + lr) * 128 + hf * 64 + ds * 32 + lg * 8);
    f32x4 O1[4] = {}, O2[4] = {};
    f32x4 Ol1 = {0.f, 0.f, 0.f, 0.f}, Ol2 = {0.f, 0.f, 0.f, 0.f};
    const int nkt = qt + 1;
    int cur = 0;
    stage(0, 0);
    __syncthreads();
    for (int kt = 0; kt < nkt; kt++) {
      if (kt + 1 < nkt) stage(cur ^ 1, (kt + 1) * KVB);  // depth-1 prefetch
      const int k0 = kt * KVB;
      // V^T B-fragments straight from global (L2-resident)
      bf16x8 vf[4];
#pragma unroll
      for (int dt = 0; dt < 4; dt++)
        vf[dt] = *(const bf16x8*)(Vbb + (size_t)(dt * 16 + lr) * 4096 + (size_t)(k0 + lg * 8) * 2);
      // QK^T
      f32x4 s1[2] = {}, s2[2] = {};
      const char* kbase = (const char*)Kl[cur];
      unsigned sw = ((unsigned)(lr & 7)) << 4;
#pragma unroll
      for (int ct = 0; ct < 2; ct++) {
        const char* kb = kbase + (ct * 16 + lr) * 256;
#pragma unroll
        for (int ds = 0; ds < 2; ds++) {
          bf16x8 kf1 = *(const bf16x8*)(kb + (((unsigned)(ds * 64 + lg * 16)) ^ sw));
          bf16x8 kf2 = *(const bf16x8*)(kb + (((unsigned)(128 + ds * 64 + lg * 16)) ^ sw));
          s1[ct] = mfma16(qf[0][ds], kf1, s1[ct]);
          s2[ct] = mfma16(qf[1][ds], kf2, s2[ct]);
        }
      }
      // causal mask (diagonal tile only), exp, pack p1|p2 (explicit, order-safe), store to P
      if (kt == nkt - 1) {
#pragma unroll
        for (int ct = 0; ct < 2; ct++)
#pragma unroll
          for (int r = 0; r < 4; r++) {
            int kg = k0 + ct * 16 + lr, qg = q0 + w * 16 + lg * 4 + r;
            if (kg > qg) { s1[ct][r] = -1e30f; s2[ct][r] = -1e30f; }
          }
      }
#pragma unroll
      for (int ct = 0; ct < 2; ct++)
#pragma unroll
        for (int r = 0; r < 4; r++) {
          float p1 = __expf(s1[ct][r]);
          float p2 = __expf(s2[ct][r]);
          uint32_t pk = (uint32_t)f2b(p1) | ((uint32_t)f2b(p2) << 16);  // p1 lo, p2 hi (known order)
          *(uint32_t*)(Pw + (lg * 4 + r) * 144 + (ct * 16 + lr) * 4) = pk;
        }
      // PV: read packed P row (q=lr), extract bf16x8 for s1 (lows) and s2 (highs)
      const char* pbp = Pw + lr * 144 + lg * 32;
      int4 pa = *(const int4*)pbp;
      int4 pc = *(const int4*)(pbp + 16);
      int4 w1 = {(int)__builtin_amdgcn_perm((unsigned)pa.y, (unsigned)pa.x, 0x05040100u),
                 (int)__builtin_amdgcn_perm((unsigned)pa.w, (unsigned)pa.z, 0x05040100u),
                 (int)__builtin_amdgcn_perm((unsigned)pc.y, (unsigned)pc.x, 0x05040100u),
                 (int)__builtin_amdgcn_perm((unsigned)pc.w, (unsigned)pc.z, 0x05040100u)};
      int4 w2 = {(int)__builtin_amdgcn_perm((unsigned)pa.y, (unsigned)pa.x, 0x07060302u),
                 (int)__builtin_amdgcn_perm((unsigned)pa.w, (unsigned)pa.z, 0x07060302u),
                 (int)__builtin_amdgcn_perm((unsigned)pc.y, (unsigned)pc.x, 0x07060302u),
                 (int)__builtin_amdgcn_perm((unsigned)pc.w, (unsigned)pc.z, 0x07060302u)};
      bf16x8 pf1 = __builtin_bit_cast(bf16x8, w1);
      bf16x8 pf2 = __builtin_bit_cast(bf16x8, w2);
#pragma unroll
      for (int dt = 0; dt < 4; dt++) {
        O1[dt] = mfma16(pf1, vf[dt], O1[dt]);
        O2[dt] = mfma16(pf2, vf[dt], O2[dt]);
      }
      Ol1 = mfma16(pf1, ones, Ol1);
      Ol2 = mfma16(pf2, ones, Ol2);
      __syncthreads();          // drains prefetch + protects K buffer reuse
      cur ^= 1;
    }
    // epilogue: diff-combine, RMSNorm over hd=64, head weight, (1-lambda_init)=0.8
    float rr[4];
    f32x4 ov[4];
#pragma unroll
    for (int r = 0; r < 4; r++) {
      float i1 = 1.f / Ol1[r], i2 = lam / Ol2[r];
      float ss = 0.f;
#pragma unroll
      for (int dt = 0; dt < 4; dt++) {
        float o = O1[dt][r] * i1 - O2[dt][r] * i2;
        ov[dt][r] = o;
        ss += o * o;
      }
#pragma unroll
      for (int d = 1; d < 16; d <<= 1) ss += __shfl_xor(ss, d);
      rr[r] = rsqrtf(ss * (1.f / 64.f) + 1e-6f) * 0.8f;
    }
#pragma unroll
    for (int dt = 0; dt < 4; dt++) {
#pragma unroll
      for (int r = 0; r < 4; r++) {
        int qg = q0 + w * 16 + lg * 4 + r;
        Aout[((size_t)b * 2048 + qg) * 1024 + h * 64 + dt * 16 + lr] = f2b(ov[dt][r] * rr[r] * hw4[dt]);
      }
    }
  }
}

// ---------------- launch ----------------
extern "C" void kernel_launch(void* const* d_in, const int* in_sizes, int n_in,
                              void* d_out, int out_size, void* d_ws, size_t ws_size,
                              hipStream_t stream) {
  const float* x   = (const float*)d_in[0];
  const float* Wq  = (const float*)d_in[1];
  const float* bq  = (const float*)d_in[2];
  const float* Wk  = (const float*)d_in[3];
  const float* bk  = (const float*)d_in[4];
  const float* Wv  = (const float*)d_in[5];
  const float* bv  = (const float*)d_in[6];
  const float* Wo  = (const float*)d_in[7];
  const float* bo  = (const float*)d_in[8];
  const float* hnw = (const float*)d_in[9];
  const float* lq1 = (const float*)d_in[10];
  const float* lk1 = (const float*)d_in[11];
  const float* lq2 = (const float*)d_in[12];
  const float* lk2 = (const float*)d_in[13];
  float* out = (float*)d_out;
  char* ws = (char*)d_ws;

  u16*   x_bf  = (u16*)(ws);                 //  8,388,608 B
  u16*   wcat  = (u16*)(ws + 8388608);       // 10,485,760 B  (Wq|Wk|Wv bf16)
  u16*   wo_bf = (u16*)(ws + 18874368);      //  2,097,152 B
  float* bcat  = (float*)(ws + 20971520);    //     20,480 B
  float* lam   = (float*)(ws + 20992000);    //         64 B
  u16*   q_r   = (u16*)(ws + 20992064);      // 16,777,216 B  (B,H,S,128)
  u16*   k_r   = (u16*)(ws + 37769280);      // 16,777,216 B
  u16*   v_t   = (u16*)(ws + 54546496);      //  8,388,608 B  (B,H,64,S)  V transposed
  u16*   a_out = (u16*)(ws + 62935104);      //  8,388,608 B

  cvt_k<<<4096, 256, 0, stream>>>(x, x_bf, 4194304);
  cvt_k<<<2048, 256, 0, stream>>>(Wq, wcat, 2097152);
  cvt_k<<<2048, 256, 0, stream>>>(Wk, wcat + 2097152, 2097152);
  cvt_k<<<1024, 256, 0, stream>>>(Wv, wcat + 4194304, 1048576);
  cvt_k<<<1024, 256, 0, stream>>>(Wo, wo_bf, 1048576);
  bcat_k<<<20, 256, 0, stream>>>(bq, bk, bv, bcat);
  lam_k<<<1, 64, 0, stream>>>(lq1, lk1, lq2, lk2, lam);
  gemm_qkv<<<dim3(40, 32), 256, 0, stream>>>(x_bf, wcat, bcat, q_r, k_r, v_t);
  rope_k<<<8192, 256, 0, stream>>>(q_r, k_r);
  diff_attn<<<1024, 128, 0, stream>>>(q_r, k_r, v_t, lam, hnw, a_out);
  gemm_wo<<<dim3(8, 32), 256, 0, stream>>>(a_out, wo_bf, bo, out);
}